// Round 19
// baseline (1766.565 us; speedup 1.0000x reference)
//
#include <hip/hip_runtime.h>
#include <cstdint>
#include <cstddef>

// ---------------------------------------------------------------------------
// CADGroupingGNN: 3x GCNConv(128->128) + MLP classifier, N=50000, E=800000.
// Round 19: 8x8-register-tile GEMM (k_gemm8) for layer-2/3 + classifier-1.
// Old GEMM was LDS-instruction-bound at 3x the VALU floor (reuse=4: 128B of
// ds_read_b128 per 256 FMAs > 128B/cyc LDS). 8x8 thread-tile doubles reuse;
// 128x128 block tile, K in 4 double-buffered chunks of 32, 68KB LDS,
// 2 blocks/CU. GEMM1(+hist) and HOUT=64 classifier-2 keep the proven kernel.
// Agg unchanged (69us gather service floor). fp32 mandatory.
// ---------------------------------------------------------------------------

// ---- scan1: unpack packed counts, deg/dinv/snorm inline, block scan ----
__global__ __launch_bounds__(256) void k_scan1(
    const int* __restrict__ cnt, int* __restrict__ start,
    int* __restrict__ bsum, const float* __restrict__ emb,
    float* __restrict__ dinv, float* __restrict__ snorm, int n) {
  __shared__ int s[256];
  int t = threadIdx.x, idx = blockIdx.x * 256 + t;
  int packed = (idx < n) ? cnt[idx] : 0;
  int c0 = packed & 1023, c1 = (packed >> 10) & 1023, c2 = (packed >> 20) & 1023;
  if (idx < n) {
    float deg = 1.0f + (float)c0 * emb[0] + (float)c1 * emb[1]
                     + (float)c2 * emb[2];
    float v = deg > 0.f ? rsqrtf(deg) : 0.f;
    dinv[idx] = v;
    snorm[idx] = v * v;
  }
  s[t] = c0 + c1 + c2;
  for (int d = 1; d < 256; d <<= 1) {
    __syncthreads();
    int x = (t >= d) ? s[t - d] : 0;
    __syncthreads();
    s[t] += x;
  }
  __syncthreads();
  if (idx < n) start[idx + 1] = s[t];          // inclusive, per-block
  if (t == 255) bsum[blockIdx.x] = s[255];
}

__global__ __launch_bounds__(256) void k_scan2(int* __restrict__ bsum, int nb) {
  __shared__ int s[256];
  int t = threadIdx.x;
  s[t] = (t < nb) ? bsum[t] : 0;
  for (int d = 1; d < 256; d <<= 1) {
    __syncthreads();
    int x = (t >= d) ? s[t - d] : 0;
    __syncthreads();
    s[t] += x;
  }
  __syncthreads();
  if (t < nb) bsum[t] = s[t];                  // inclusive block sums
}

__global__ __launch_bounds__(256) void k_scan3(
    int* __restrict__ start, const int* __restrict__ bsum, int n) {
  int b = blockIdx.x, idx = b * 256 + threadIdx.x;
  if (idx < n) {
    int off = (b > 0) ? bsum[b - 1] : 0;
    start[idx + 1] += off;
    if (idx == 0) start[0] = 0;
  }
}

// atomic-free bucket fill: p = start[col] + rank; writes src + FINAL weight
__global__ __launch_bounds__(256) void k_fill(
    const int* __restrict__ attr, const float* __restrict__ emb,
    const int* __restrict__ row, const int* __restrict__ col,
    const int* __restrict__ rank, const int* __restrict__ start,
    const float* __restrict__ dinv, int* __restrict__ srcs,
    float* __restrict__ wts, int E) {
  int e = blockIdx.x * 256 + threadIdx.x;
  if (e < E) {
    int r = row[e], c = col[e];
    int p = start[c] + rank[e];
    srcs[p] = r;
    wts[p] = dinv[r] * emb[attr[e]] * dinv[c];
  }
}

__device__ __forceinline__ void agg_fma(float s, const float4& v, float4& acc) {
  acc.x = fmaf(s, v.x, acc.x);
  acc.y = fmaf(s, v.y, acc.y);
  acc.z = fmaf(s, v.z, acc.z);
  acc.w = fmaf(s, v.w, acc.w);
}

// out[i][:] = bias + snorm[i]*h[i][:] + sum_e wts[e]*h[srcs[e]][:]
// 32 lanes per node, float4 per lane (128 channels). 8-deep gather pipeline.
__global__ __launch_bounds__(256) void k_agg_csr(
    const float* __restrict__ h, const int* __restrict__ start,
    const int* __restrict__ srcs, const float* __restrict__ wts,
    const float* __restrict__ snorm, const float* __restrict__ bias,
    float* __restrict__ out, int n) {
  int tid = blockIdx.x * 256 + threadIdx.x;
  int i = tid >> 5;
  if (i >= n) return;
  int lane = tid & 31;
  const float4* h4 = (const float4*)h;
  float4 acc = ((const float4*)bias)[lane];
  float sn = snorm[i];
  float4 hv = h4[(size_t)i * 32 + lane];
  agg_fma(sn, hv, acc);

  int e = start[i], eend = start[i + 1];

  while (e < eend && (e & 3)) {
    float w = wts[e];
    float4 v = h4[(size_t)srcs[e] * 32 + lane];
    agg_fma(w, v, acc);
    ++e;
  }

  for (; e + 8 <= eend; e += 8) {
    int4   s0 = *(const int4*)&srcs[e];
    int4   s1 = *(const int4*)&srcs[e + 4];
    float4 w0 = *(const float4*)&wts[e];
    float4 w1 = *(const float4*)&wts[e + 4];
    float4 v0 = h4[(size_t)s0.x * 32 + lane];
    float4 v1 = h4[(size_t)s0.y * 32 + lane];
    float4 v2 = h4[(size_t)s0.z * 32 + lane];
    float4 v3 = h4[(size_t)s0.w * 32 + lane];
    float4 v4 = h4[(size_t)s1.x * 32 + lane];
    float4 v5 = h4[(size_t)s1.y * 32 + lane];
    float4 v6 = h4[(size_t)s1.z * 32 + lane];
    float4 v7 = h4[(size_t)s1.w * 32 + lane];
    agg_fma(w0.x, v0, acc); agg_fma(w0.y, v1, acc);
    agg_fma(w0.z, v2, acc); agg_fma(w0.w, v3, acc);
    agg_fma(w1.x, v4, acc); agg_fma(w1.y, v5, acc);
    agg_fma(w1.z, v6, acc); agg_fma(w1.w, v7, acc);
  }

  if (e + 4 <= eend) {
    int4   s0 = *(const int4*)&srcs[e];
    float4 w0 = *(const float4*)&wts[e];
    float4 v0 = h4[(size_t)s0.x * 32 + lane];
    float4 v1 = h4[(size_t)s0.y * 32 + lane];
    float4 v2 = h4[(size_t)s0.z * 32 + lane];
    float4 v3 = h4[(size_t)s0.w * 32 + lane];
    agg_fma(w0.x, v0, acc); agg_fma(w0.y, v1, acc);
    agg_fma(w0.z, v2, acc); agg_fma(w0.w, v3, acc);
    e += 4;
  }

  for (; e < eend; ++e) {
    float w = wts[e];
    float4 v = h4[(size_t)srcs[e] * 32 + lane];
    agg_fma(w, v, acc);
  }

  ((float4*)out)[(size_t)i * 32 + lane] = acc;
}

__device__ __forceinline__ void fma4(float4& a, float s, const float4& w) {
  a.x = fmaf(s, w.x, a.x);
  a.y = fmaf(s, w.y, a.y);
  a.z = fmaf(s, w.z, a.z);
  a.w = fmaf(s, w.w, a.w);
}

// 8x8-register-tile GEMM: out[M x 128] = act( f(A) @ W + bias ).
// 256 thr, tile 128x128, thread = rows {tr*4+rr, 64+tr*4+rr} x cols
// {tc*4..+3, 64+tc*4..+3}. K in 4 double-buffered chunks of 32.
// ACT: 0 none, 1 relu. RELU_IN: relu on A load.
template <int ACT, bool RELU_IN>
__global__ __launch_bounds__(256, 2) void k_gemm8(
    const float* __restrict__ A, const float* __restrict__ W,
    const float* __restrict__ bias, float* __restrict__ out, int M) {
  __shared__ float Xs[2][128][36];   // 36.9 KB (pad 36: 2-way bank = free)
  __shared__ float Ws[2][32][128];   // 32 KB
  const int t = threadIdx.x;
  const int tc = t & 15;
  const int tr = t >> 4;
  const int m0 = blockIdx.x * 128;
  const float4* A4 = (const float4*)A;
  const float4* W4 = (const float4*)W;

  // stage chunk 0
#pragma unroll
  for (int q = 0; q < 4; ++q) {
    int idx = q * 256 + t;
    int row = idx >> 3, kq = idx & 7;
    int gr = m0 + row;
    float4 v = make_float4(0.f, 0.f, 0.f, 0.f);
    if (gr < M) v = A4[(size_t)gr * 32 + kq];
    if (RELU_IN) {
      v.x = fmaxf(v.x, 0.f); v.y = fmaxf(v.y, 0.f);
      v.z = fmaxf(v.z, 0.f); v.w = fmaxf(v.w, 0.f);
    }
    *(float4*)&Xs[0][row][kq * 4] = v;
    int k = idx >> 5, cq = idx & 31;
    *(float4*)&Ws[0][k][cq * 4] = W4[(size_t)k * 32 + cq];
  }
  __syncthreads();

  float4 acc[8][2];
#pragma unroll
  for (int rr = 0; rr < 8; ++rr) {
    acc[rr][0] = make_float4(0.f, 0.f, 0.f, 0.f);
    acc[rr][1] = make_float4(0.f, 0.f, 0.f, 0.f);
  }

  float4 preX[4], preW[4];
#pragma unroll
  for (int kc = 0; kc < 4; ++kc) {
    if (kc < 3) {   // issue next chunk's global loads now
#pragma unroll
      for (int q = 0; q < 4; ++q) {
        int idx = q * 256 + t;
        int row = idx >> 3, kq = idx & 7;
        int gr = m0 + row;
        preX[q] = (gr < M) ? A4[(size_t)gr * 32 + (kc + 1) * 8 + kq]
                           : make_float4(0.f, 0.f, 0.f, 0.f);
        int k = idx >> 5, cq = idx & 31;
        preW[q] = W4[(size_t)((kc + 1) * 32 + k) * 32 + cq];
      }
    }
    const int b = kc & 1;
#pragma unroll
    for (int k4 = 0; k4 < 8; ++k4) {
      float4 av[8], wv[4][2];
#pragma unroll
      for (int rr = 0; rr < 4; ++rr) {
        av[rr]     = *(const float4*)&Xs[b][tr * 4 + rr][k4 * 4];
        av[rr + 4] = *(const float4*)&Xs[b][64 + tr * 4 + rr][k4 * 4];
      }
#pragma unroll
      for (int kk = 0; kk < 4; ++kk) {
        wv[kk][0] = *(const float4*)&Ws[b][k4 * 4 + kk][tc * 4];
        wv[kk][1] = *(const float4*)&Ws[b][k4 * 4 + kk][64 + tc * 4];
      }
#pragma unroll
      for (int rr = 0; rr < 8; ++rr) {
        fma4(acc[rr][0], av[rr].x, wv[0][0]);
        fma4(acc[rr][1], av[rr].x, wv[0][1]);
        fma4(acc[rr][0], av[rr].y, wv[1][0]);
        fma4(acc[rr][1], av[rr].y, wv[1][1]);
        fma4(acc[rr][0], av[rr].z, wv[2][0]);
        fma4(acc[rr][1], av[rr].z, wv[2][1]);
        fma4(acc[rr][0], av[rr].w, wv[3][0]);
        fma4(acc[rr][1], av[rr].w, wv[3][1]);
      }
    }
    if (kc < 3) {
      __syncthreads();   // all reads of buf b done elsewhere too
#pragma unroll
      for (int q = 0; q < 4; ++q) {
        int idx = q * 256 + t;
        int row = idx >> 3, kq = idx & 7;
        float4 v = preX[q];
        if (RELU_IN) {
          v.x = fmaxf(v.x, 0.f); v.y = fmaxf(v.y, 0.f);
          v.z = fmaxf(v.z, 0.f); v.w = fmaxf(v.w, 0.f);
        }
        *(float4*)&Xs[b ^ 1][row][kq * 4] = v;
        int k = idx >> 5, cq = idx & 31;
        *(float4*)&Ws[b ^ 1][k][cq * 4] = preW[q];
      }
      __syncthreads();
    }
  }

  // epilogue
#pragma unroll
  for (int rr = 0; rr < 8; ++rr) {
    int row = (rr < 4) ? (tr * 4 + rr) : (64 + tr * 4 + (rr - 4));
    int gr = m0 + row;
    if (gr >= M) continue;
#pragma unroll
    for (int h = 0; h < 2; ++h) {
      float4 v = acc[rr][h];
      int c4 = tc + h * 16;
      if (bias) {
        const float4 bv = ((const float4*)bias)[c4];
        v.x += bv.x; v.y += bv.y; v.z += bv.z; v.w += bv.w;
      }
      if (ACT == 1) {
        v.x = fmaxf(v.x, 0.f); v.y = fmaxf(v.y, 0.f);
        v.z = fmaxf(v.z, 0.f); v.w = fmaxf(v.w, 0.f);
      }
      ((float4*)out)[(size_t)gr * 32 + c4] = v;
    }
  }
}

// Original GEMM (4x4 tile): used for layer-1 (+interleaved packed hist) and
// the HOUT=64 classifier-2. ACT: 0 none, 1 relu, 2 sigmoid.
template <int HOUT, int ACT, bool RELU_IN, bool HIST>
__global__ __launch_bounds__(256, 2) void k_gemm(
    const float* __restrict__ A, const float* __restrict__ W,
    const float* __restrict__ bias, float* __restrict__ out, int M,
    const int* __restrict__ hcol, const int* __restrict__ hattr,
    int* __restrict__ hcnt, int* __restrict__ hrank, int E) {
  constexpr int NCT = HOUT / 64;   // column tiles
  constexpr int W4R = HOUT / 4;    // float4 per W row
  __shared__ float Ws[128 * 64];   // 32 KB
  __shared__ float Xs[64][132];    // 33 KB

  const int t = threadIdx.x;
  const int ct = blockIdx.x % NCT;
  const int rt0 = blockIdx.x / NCT;
  const int rstride = gridDim.x / NCT;
  const int ntiles = (M + 63) >> 6;

  for (int i = t; i < 128 * 16; i += 256) {
    int k = i >> 4, j4 = i & 15;
    ((float4*)Ws)[i] = ((const float4*)W)[k * W4R + ct * 16 + j4];
  }

  const int tc = t & 15;
  const int tr = t >> 4;
  const float4* A4 = (const float4*)A;
  const int r0 = t >> 5, c40 = t & 31;

  const int g = blockIdx.x * 256 + t;
  const int G = gridDim.x * 256;
  int jtile = 0;

  float4 pre[8];
  auto load_tile = [&](int rt) {
#pragma unroll
    for (int q = 0; q < 8; ++q) {
      int gr = (rt << 6) + r0 + q * 8;
      pre[q] = (gr < M) ? A4[(size_t)gr * 32 + c40]
                        : make_float4(0.f, 0.f, 0.f, 0.f);
    }
  };
  auto store_tile = [&]() {
#pragma unroll
    for (int q = 0; q < 8; ++q) {
      float4 v = pre[q];
      if (RELU_IN) {
        v.x = fmaxf(v.x, 0.f); v.y = fmaxf(v.y, 0.f);
        v.z = fmaxf(v.z, 0.f); v.w = fmaxf(v.w, 0.f);
      }
      *(float4*)&Xs[r0 + q * 8][c40 * 4] = v;
    }
  };

  if (rt0 < ntiles) {
    load_tile(rt0);
    __syncthreads();
    store_tile();
    __syncthreads();

    for (int rt = rt0; rt < ntiles; rt += rstride) {
      const int nxt = rt + rstride;
      if (nxt < ntiles) load_tile(nxt);

      int he0 = -1, he1 = -1, he2 = -1;
      int hr0 = 0, hr1 = 0, hr2 = 0;
      if (HIST) {
        int base = (jtile * 3) * G + g;
        if (base < E) {
          he0 = base;
          hr0 = atomicAdd(&hcnt[hcol[he0]], 1 << (10 * hattr[he0]));
        }
        if (base + G < E) {
          he1 = base + G;
          hr1 = atomicAdd(&hcnt[hcol[he1]], 1 << (10 * hattr[he1]));
        }
        if (base + 2 * G < E) {
          he2 = base + 2 * G;
          hr2 = atomicAdd(&hcnt[hcol[he2]], 1 << (10 * hattr[he2]));
        }
      }

      const int m0 = rt << 6;
      float acc[4][4];
#pragma unroll
      for (int rr = 0; rr < 4; ++rr)
        acc[rr][0] = acc[rr][1] = acc[rr][2] = acc[rr][3] = 0.f;

#pragma unroll 4
      for (int k4 = 0; k4 < 32; ++k4) {
        float4 wv[4], av[4];
#pragma unroll
        for (int kk = 0; kk < 4; ++kk)
          wv[kk] = ((const float4*)Ws)[(k4 * 4 + kk) * 16 + tc];
#pragma unroll
        for (int rr = 0; rr < 4; ++rr)
          av[rr] = *(const float4*)&Xs[tr * 4 + rr][k4 * 4];
#pragma unroll
        for (int rr = 0; rr < 4; ++rr) {
          acc[rr][0] = fmaf(av[rr].x, wv[0].x, acc[rr][0]);
          acc[rr][1] = fmaf(av[rr].x, wv[0].y, acc[rr][1]);
          acc[rr][2] = fmaf(av[rr].x, wv[0].z, acc[rr][2]);
          acc[rr][3] = fmaf(av[rr].x, wv[0].w, acc[rr][3]);
          acc[rr][0] = fmaf(av[rr].y, wv[1].x, acc[rr][0]);
          acc[rr][1] = fmaf(av[rr].y, wv[1].y, acc[rr][1]);
          acc[rr][2] = fmaf(av[rr].y, wv[1].z, acc[rr][2]);
          acc[rr][3] = fmaf(av[rr].y, wv[1].w, acc[rr][3]);
          acc[rr][0] = fmaf(av[rr].z, wv[2].x, acc[rr][0]);
          acc[rr][1] = fmaf(av[rr].z, wv[2].y, acc[rr][1]);
          acc[rr][2] = fmaf(av[rr].z, wv[2].z, acc[rr][2]);
          acc[rr][3] = fmaf(av[rr].z, wv[2].w, acc[rr][3]);
          acc[rr][0] = fmaf(av[rr].w, wv[3].x, acc[rr][0]);
          acc[rr][1] = fmaf(av[rr].w, wv[3].y, acc[rr][1]);
          acc[rr][2] = fmaf(av[rr].w, wv[3].z, acc[rr][2]);
          acc[rr][3] = fmaf(av[rr].w, wv[3].w, acc[rr][3]);
        }
      }

#pragma unroll
      for (int rr = 0; rr < 4; ++rr) {
        int gr = m0 + tr * 4 + rr;
        if (gr >= M) continue;
        float4 v = make_float4(acc[rr][0], acc[rr][1], acc[rr][2], acc[rr][3]);
        if (bias) {
          const float4 bv = *(const float4*)&bias[ct * 64 + tc * 4];
          v.x += bv.x; v.y += bv.y; v.z += bv.z; v.w += bv.w;
        }
        if (ACT == 1) {
          v.x = fmaxf(v.x, 0.f); v.y = fmaxf(v.y, 0.f);
          v.z = fmaxf(v.z, 0.f); v.w = fmaxf(v.w, 0.f);
        } else if (ACT == 2) {
          v.x = 1.f / (1.f + __expf(-v.x));
          v.y = 1.f / (1.f + __expf(-v.y));
          v.z = 1.f / (1.f + __expf(-v.z));
          v.w = 1.f / (1.f + __expf(-v.w));
        }
        ((float4*)out)[(size_t)gr * W4R + ct * 16 + tc] = v;
      }

      if (HIST) {
        if (he0 >= 0)
          hrank[he0] = (hr0 & 1023) + ((hr0 >> 10) & 1023) + ((hr0 >> 20) & 1023);
        if (he1 >= 0)
          hrank[he1] = (hr1 & 1023) + ((hr1 >> 10) & 1023) + ((hr1 >> 20) & 1023);
        if (he2 >= 0)
          hrank[he2] = (hr2 & 1023) + ((hr2 >> 10) & 1023) + ((hr2 >> 20) & 1023);
        ++jtile;
      }

      if (nxt < ntiles) {
        __syncthreads();
        store_tile();
        __syncthreads();
      }
    }
  }

  if (HIST) {
    for (long long m = 3LL * jtile;; ++m) {
      long long e = m * G + g;
      if (e >= E) break;
      int a = hattr[e];
      int old = atomicAdd(&hcnt[hcol[e]], 1 << (10 * a));
      hrank[e] = (old & 1023) + ((old >> 10) & 1023) + ((old >> 20) & 1023);
    }
  }
}

extern "C" void kernel_launch(void* const* d_in, const int* in_sizes, int n_in,
                              void* d_out, int out_size, void* d_ws, size_t ws_size,
                              hipStream_t stream) {
  const float* x        = (const float*)d_in[0];
  const float* edge_emb = (const float*)d_in[1];
  const float* W1 = (const float*)d_in[2];  const float* b1 = (const float*)d_in[3];
  const float* W2 = (const float*)d_in[4];  const float* b2 = (const float*)d_in[5];
  const float* W3 = (const float*)d_in[6];  const float* b3 = (const float*)d_in[7];
  const float* cW1 = (const float*)d_in[8]; const float* cb1 = (const float*)d_in[9];
  const float* cW2 = (const float*)d_in[10]; const float* cb2 = (const float*)d_in[11];
  const int* eidx  = (const int*)d_in[12];
  const int* eattr = (const int*)d_in[13];

  const int N = in_sizes[0] / 128;
  const int E = in_sizes[13];
  const int* row = eidx;        // edge_index[0] = source
  const int* col = eidx + E;    // edge_index[1] = target

  float* out = (float*)d_out;

  // workspace layout, 16B-aligned slots (element counts rounded to x4)
  size_t off = 0;
  auto alloc4 = [&](size_t n) { size_t o = off; off += (n + 3) & ~(size_t)3; return o; };
  float* wsf = (float*)d_ws;
  int*   wsi = (int*)d_ws;

  float* dinv   = wsf + alloc4(N);
  float* snorm  = wsf + alloc4(N);
  int*   cnt    = wsi + alloc4(N);       // packed 3x10-bit per-attr counts
  int*   start  = wsi + alloc4(N + 1);
  int*   bsum   = wsi + alloc4(256);
  int*   rank   = wsi + alloc4(E);
  int*   srcs   = wsi + alloc4(E);
  float* wts    = wsf + alloc4(E);       // final normalized weights
  float* bufA   = wsf + alloc4((size_t)N * 128);
  float* bufB   = wsf + alloc4((size_t)N * 128);

  const int gN  = (N + 255) / 256;
  const int gE  = (E + 255) / 256;
  const int gA  = (N * 32 + 255) / 256;
  const int nb  = gN;  // scan blocks
  const int gGemm = 512;               // persistent old GEMM: 2 blocks/CU
  const int gG8   = (N + 127) / 128;   // 8x8 GEMM: one 128-row tile/block

  // cnt must be zero before the interleaved hist in the layer-1 GEMM
  (void)hipMemsetAsync(cnt, 0, (size_t)N * sizeof(int), stream);

  // ---- layer-1 GEMM with interleaved packed edge histogram ----
  k_gemm<128, 0, false, true><<<gGemm, 256, 0, stream>>>(
      x, W1, nullptr, bufA, N, col, eattr, cnt, rank, E);

  // ---- CSR build: scan (+deg/dinv/snorm inline) -> fill (normalized) ----
  k_scan1<<<nb, 256, 0, stream>>>(cnt, start, bsum, edge_emb, dinv, snorm, N);
  k_scan2<<<1, 256, 0, stream>>>(bsum, nb);
  k_scan3<<<nb, 256, 0, stream>>>(start, bsum, N);
  k_fill<<<gE, 256, 0, stream>>>(eattr, edge_emb, row, col, rank, start,
                                 dinv, srcs, wts, E);

  // ---- layer 1 agg ----
  k_agg_csr<<<gA, 256, 0, stream>>>(bufA, start, srcs, wts, snorm, b1, bufB, N);
  // ---- layer 2 (8x8 GEMM) ----
  k_gemm8<0, true><<<gG8, 256, 0, stream>>>(bufB, W2, nullptr, bufA, N);
  k_agg_csr<<<gA, 256, 0, stream>>>(bufA, start, srcs, wts, snorm, b2, bufB, N);
  // ---- layer 3 (8x8 GEMM) ----
  k_gemm8<0, true><<<gG8, 256, 0, stream>>>(bufB, W3, nullptr, bufA, N);
  k_agg_csr<<<gA, 256, 0, stream>>>(bufA, start, srcs, wts, snorm, b3, bufB, N);

  // ---- classifier ----
  k_gemm8<1, true><<<gG8, 256, 0, stream>>>(bufB, cW1, cb1, bufA, N);
  k_gemm<64, 2, false, false><<<gGemm, 256, 0, stream>>>(
      bufA, cW2, cb2, out, N, nullptr, nullptr, nullptr, nullptr, 0);
}

// Round 20
// 410.117 us; speedup vs baseline: 4.3075x; 4.3075x over previous
//
#include <hip/hip_runtime.h>
#include <cstdint>
#include <cstddef>

// ---------------------------------------------------------------------------
// CADGroupingGNN: 3x GCNConv(128->128) + MLP classifier, N=50000, E=800000.
// Round 20: REVERT to round-18 (proven best, 409.8us). Round-19's 8x8 GEMM
// spilled (acc+prefetch ~160 VGPR > 128 cap at 2 blocks/CU -> 1.3GB scratch
// traffic). Keeping: packed 3-field histogram interleaved in GEMM1 (attr in
// {0,1,2}), deg/dinv/snorm inline in scan1, fill writes final normalized
// weights, 4x4-tile k_gemm (2 blocks/CU), round-6 agg (69us gather floor).
// fp32 mandatory (bf16/fp16 flip saturated sigmoids via snorm~1e4 amplify).
// ---------------------------------------------------------------------------

// ---- scan1: unpack packed counts, deg/dinv/snorm inline, block scan ----
__global__ __launch_bounds__(256) void k_scan1(
    const int* __restrict__ cnt, int* __restrict__ start,
    int* __restrict__ bsum, const float* __restrict__ emb,
    float* __restrict__ dinv, float* __restrict__ snorm, int n) {
  __shared__ int s[256];
  int t = threadIdx.x, idx = blockIdx.x * 256 + t;
  int packed = (idx < n) ? cnt[idx] : 0;
  int c0 = packed & 1023, c1 = (packed >> 10) & 1023, c2 = (packed >> 20) & 1023;
  if (idx < n) {
    float deg = 1.0f + (float)c0 * emb[0] + (float)c1 * emb[1]
                     + (float)c2 * emb[2];
    float v = deg > 0.f ? rsqrtf(deg) : 0.f;
    dinv[idx] = v;
    snorm[idx] = v * v;
  }
  s[t] = c0 + c1 + c2;
  for (int d = 1; d < 256; d <<= 1) {
    __syncthreads();
    int x = (t >= d) ? s[t - d] : 0;
    __syncthreads();
    s[t] += x;
  }
  __syncthreads();
  if (idx < n) start[idx + 1] = s[t];          // inclusive, per-block
  if (t == 255) bsum[blockIdx.x] = s[255];
}

__global__ __launch_bounds__(256) void k_scan2(int* __restrict__ bsum, int nb) {
  __shared__ int s[256];
  int t = threadIdx.x;
  s[t] = (t < nb) ? bsum[t] : 0;
  for (int d = 1; d < 256; d <<= 1) {
    __syncthreads();
    int x = (t >= d) ? s[t - d] : 0;
    __syncthreads();
    s[t] += x;
  }
  __syncthreads();
  if (t < nb) bsum[t] = s[t];                  // inclusive block sums
}

__global__ __launch_bounds__(256) void k_scan3(
    int* __restrict__ start, const int* __restrict__ bsum, int n) {
  int b = blockIdx.x, idx = b * 256 + threadIdx.x;
  if (idx < n) {
    int off = (b > 0) ? bsum[b - 1] : 0;
    start[idx + 1] += off;
    if (idx == 0) start[0] = 0;
  }
}

// atomic-free bucket fill: p = start[col] + rank; writes src + FINAL weight
__global__ __launch_bounds__(256) void k_fill(
    const int* __restrict__ attr, const float* __restrict__ emb,
    const int* __restrict__ row, const int* __restrict__ col,
    const int* __restrict__ rank, const int* __restrict__ start,
    const float* __restrict__ dinv, int* __restrict__ srcs,
    float* __restrict__ wts, int E) {
  int e = blockIdx.x * 256 + threadIdx.x;
  if (e < E) {
    int r = row[e], c = col[e];
    int p = start[c] + rank[e];
    srcs[p] = r;
    wts[p] = dinv[r] * emb[attr[e]] * dinv[c];
  }
}

__device__ __forceinline__ void agg_fma(float s, const float4& v, float4& acc) {
  acc.x = fmaf(s, v.x, acc.x);
  acc.y = fmaf(s, v.y, acc.y);
  acc.z = fmaf(s, v.z, acc.z);
  acc.w = fmaf(s, v.w, acc.w);
}

// out[i][:] = bias + snorm[i]*h[i][:] + sum_e wts[e]*h[srcs[e]][:]
// 32 lanes per node, float4 per lane (128 channels). 8-deep gather pipeline.
__global__ __launch_bounds__(256) void k_agg_csr(
    const float* __restrict__ h, const int* __restrict__ start,
    const int* __restrict__ srcs, const float* __restrict__ wts,
    const float* __restrict__ snorm, const float* __restrict__ bias,
    float* __restrict__ out, int n) {
  int tid = blockIdx.x * 256 + threadIdx.x;
  int i = tid >> 5;
  if (i >= n) return;
  int lane = tid & 31;
  const float4* h4 = (const float4*)h;
  float4 acc = ((const float4*)bias)[lane];
  float sn = snorm[i];
  float4 hv = h4[(size_t)i * 32 + lane];
  agg_fma(sn, hv, acc);

  int e = start[i], eend = start[i + 1];

  while (e < eend && (e & 3)) {
    float w = wts[e];
    float4 v = h4[(size_t)srcs[e] * 32 + lane];
    agg_fma(w, v, acc);
    ++e;
  }

  for (; e + 8 <= eend; e += 8) {
    int4   s0 = *(const int4*)&srcs[e];
    int4   s1 = *(const int4*)&srcs[e + 4];
    float4 w0 = *(const float4*)&wts[e];
    float4 w1 = *(const float4*)&wts[e + 4];
    float4 v0 = h4[(size_t)s0.x * 32 + lane];
    float4 v1 = h4[(size_t)s0.y * 32 + lane];
    float4 v2 = h4[(size_t)s0.z * 32 + lane];
    float4 v3 = h4[(size_t)s0.w * 32 + lane];
    float4 v4 = h4[(size_t)s1.x * 32 + lane];
    float4 v5 = h4[(size_t)s1.y * 32 + lane];
    float4 v6 = h4[(size_t)s1.z * 32 + lane];
    float4 v7 = h4[(size_t)s1.w * 32 + lane];
    agg_fma(w0.x, v0, acc); agg_fma(w0.y, v1, acc);
    agg_fma(w0.z, v2, acc); agg_fma(w0.w, v3, acc);
    agg_fma(w1.x, v4, acc); agg_fma(w1.y, v5, acc);
    agg_fma(w1.z, v6, acc); agg_fma(w1.w, v7, acc);
  }

  if (e + 4 <= eend) {
    int4   s0 = *(const int4*)&srcs[e];
    float4 w0 = *(const float4*)&wts[e];
    float4 v0 = h4[(size_t)s0.x * 32 + lane];
    float4 v1 = h4[(size_t)s0.y * 32 + lane];
    float4 v2 = h4[(size_t)s0.z * 32 + lane];
    float4 v3 = h4[(size_t)s0.w * 32 + lane];
    agg_fma(w0.x, v0, acc); agg_fma(w0.y, v1, acc);
    agg_fma(w0.z, v2, acc); agg_fma(w0.w, v3, acc);
    e += 4;
  }

  for (; e < eend; ++e) {
    float w = wts[e];
    float4 v = h4[(size_t)srcs[e] * 32 + lane];
    agg_fma(w, v, acc);
  }

  ((float4*)out)[(size_t)i * 32 + lane] = acc;
}

// GEMM: out[M x HOUT] = act( f(A[M x 128]) @ W[128 x HOUT] + bias )
// BN=64 col tiles; persistent; 2 blocks/CU; register-prefetch pipeline.
// ACT: 0 none, 1 relu, 2 sigmoid. RELU_IN: relu on A load.
// HIST: interleave packed edge histogram (atomic 1<<(10*attr); field-sum of
// old value = dense in-bucket rank) with the tile loop.
template <int HOUT, int ACT, bool RELU_IN, bool HIST>
__global__ __launch_bounds__(256, 2) void k_gemm(
    const float* __restrict__ A, const float* __restrict__ W,
    const float* __restrict__ bias, float* __restrict__ out, int M,
    const int* __restrict__ hcol, const int* __restrict__ hattr,
    int* __restrict__ hcnt, int* __restrict__ hrank, int E) {
  constexpr int NCT = HOUT / 64;   // column tiles
  constexpr int W4R = HOUT / 4;    // float4 per W row
  __shared__ float Ws[128 * 64];   // 32 KB
  __shared__ float Xs[64][132];    // 33 KB

  const int t = threadIdx.x;
  const int ct = blockIdx.x % NCT;
  const int rt0 = blockIdx.x / NCT;
  const int rstride = gridDim.x / NCT;
  const int ntiles = (M + 63) >> 6;

  for (int i = t; i < 128 * 16; i += 256) {
    int k = i >> 4, j4 = i & 15;
    ((float4*)Ws)[i] = ((const float4*)W)[k * W4R + ct * 16 + j4];
  }

  const int tc = t & 15;
  const int tr = t >> 4;
  const float4* A4 = (const float4*)A;
  const int r0 = t >> 5, c40 = t & 31;

  const int g = blockIdx.x * 256 + t;
  const int G = gridDim.x * 256;
  int jtile = 0;

  float4 pre[8];
  auto load_tile = [&](int rt) {
#pragma unroll
    for (int q = 0; q < 8; ++q) {
      int gr = (rt << 6) + r0 + q * 8;
      pre[q] = (gr < M) ? A4[(size_t)gr * 32 + c40]
                        : make_float4(0.f, 0.f, 0.f, 0.f);
    }
  };
  auto store_tile = [&]() {
#pragma unroll
    for (int q = 0; q < 8; ++q) {
      float4 v = pre[q];
      if (RELU_IN) {
        v.x = fmaxf(v.x, 0.f); v.y = fmaxf(v.y, 0.f);
        v.z = fmaxf(v.z, 0.f); v.w = fmaxf(v.w, 0.f);
      }
      *(float4*)&Xs[r0 + q * 8][c40 * 4] = v;
    }
  };

  if (rt0 < ntiles) {
    load_tile(rt0);
    __syncthreads();
    store_tile();
    __syncthreads();

    for (int rt = rt0; rt < ntiles; rt += rstride) {
      const int nxt = rt + rstride;
      if (nxt < ntiles) load_tile(nxt);

      int he0 = -1, he1 = -1, he2 = -1;
      int hr0 = 0, hr1 = 0, hr2 = 0;
      if (HIST) {
        int base = (jtile * 3) * G + g;
        if (base < E) {
          he0 = base;
          hr0 = atomicAdd(&hcnt[hcol[he0]], 1 << (10 * hattr[he0]));
        }
        if (base + G < E) {
          he1 = base + G;
          hr1 = atomicAdd(&hcnt[hcol[he1]], 1 << (10 * hattr[he1]));
        }
        if (base + 2 * G < E) {
          he2 = base + 2 * G;
          hr2 = atomicAdd(&hcnt[hcol[he2]], 1 << (10 * hattr[he2]));
        }
      }

      const int m0 = rt << 6;
      float acc[4][4];
#pragma unroll
      for (int rr = 0; rr < 4; ++rr)
        acc[rr][0] = acc[rr][1] = acc[rr][2] = acc[rr][3] = 0.f;

#pragma unroll 4
      for (int k4 = 0; k4 < 32; ++k4) {
        float4 wv[4], av[4];
#pragma unroll
        for (int kk = 0; kk < 4; ++kk)
          wv[kk] = ((const float4*)Ws)[(k4 * 4 + kk) * 16 + tc];
#pragma unroll
        for (int rr = 0; rr < 4; ++rr)
          av[rr] = *(const float4*)&Xs[tr * 4 + rr][k4 * 4];
#pragma unroll
        for (int rr = 0; rr < 4; ++rr) {
          acc[rr][0] = fmaf(av[rr].x, wv[0].x, acc[rr][0]);
          acc[rr][1] = fmaf(av[rr].x, wv[0].y, acc[rr][1]);
          acc[rr][2] = fmaf(av[rr].x, wv[0].z, acc[rr][2]);
          acc[rr][3] = fmaf(av[rr].x, wv[0].w, acc[rr][3]);
          acc[rr][0] = fmaf(av[rr].y, wv[1].x, acc[rr][0]);
          acc[rr][1] = fmaf(av[rr].y, wv[1].y, acc[rr][1]);
          acc[rr][2] = fmaf(av[rr].y, wv[1].z, acc[rr][2]);
          acc[rr][3] = fmaf(av[rr].y, wv[1].w, acc[rr][3]);
          acc[rr][0] = fmaf(av[rr].z, wv[2].x, acc[rr][0]);
          acc[rr][1] = fmaf(av[rr].z, wv[2].y, acc[rr][1]);
          acc[rr][2] = fmaf(av[rr].z, wv[2].z, acc[rr][2]);
          acc[rr][3] = fmaf(av[rr].z, wv[2].w, acc[rr][3]);
          acc[rr][0] = fmaf(av[rr].w, wv[3].x, acc[rr][0]);
          acc[rr][1] = fmaf(av[rr].w, wv[3].y, acc[rr][1]);
          acc[rr][2] = fmaf(av[rr].w, wv[3].z, acc[rr][2]);
          acc[rr][3] = fmaf(av[rr].w, wv[3].w, acc[rr][3]);
        }
      }

#pragma unroll
      for (int rr = 0; rr < 4; ++rr) {
        int gr = m0 + tr * 4 + rr;
        if (gr >= M) continue;
        float4 v = make_float4(acc[rr][0], acc[rr][1], acc[rr][2], acc[rr][3]);
        if (bias) {
          const float4 bv = *(const float4*)&bias[ct * 64 + tc * 4];
          v.x += bv.x; v.y += bv.y; v.z += bv.z; v.w += bv.w;
        }
        if (ACT == 1) {
          v.x = fmaxf(v.x, 0.f); v.y = fmaxf(v.y, 0.f);
          v.z = fmaxf(v.z, 0.f); v.w = fmaxf(v.w, 0.f);
        } else if (ACT == 2) {
          v.x = 1.f / (1.f + __expf(-v.x));
          v.y = 1.f / (1.f + __expf(-v.y));
          v.z = 1.f / (1.f + __expf(-v.z));
          v.w = 1.f / (1.f + __expf(-v.w));
        }
        ((float4*)out)[(size_t)gr * W4R + ct * 16 + tc] = v;
      }

      if (HIST) {
        if (he0 >= 0)
          hrank[he0] = (hr0 & 1023) + ((hr0 >> 10) & 1023) + ((hr0 >> 20) & 1023);
        if (he1 >= 0)
          hrank[he1] = (hr1 & 1023) + ((hr1 >> 10) & 1023) + ((hr1 >> 20) & 1023);
        if (he2 >= 0)
          hrank[he2] = (hr2 & 1023) + ((hr2 >> 10) & 1023) + ((hr2 >> 20) & 1023);
        ++jtile;
      }

      if (nxt < ntiles) {
        __syncthreads();
        store_tile();
        __syncthreads();
      }
    }
  }

  if (HIST) {
    for (long long m = 3LL * jtile;; ++m) {
      long long e = m * G + g;
      if (e >= E) break;
      int a = hattr[e];
      int old = atomicAdd(&hcnt[hcol[e]], 1 << (10 * a));
      hrank[e] = (old & 1023) + ((old >> 10) & 1023) + ((old >> 20) & 1023);
    }
  }
}

extern "C" void kernel_launch(void* const* d_in, const int* in_sizes, int n_in,
                              void* d_out, int out_size, void* d_ws, size_t ws_size,
                              hipStream_t stream) {
  const float* x        = (const float*)d_in[0];
  const float* edge_emb = (const float*)d_in[1];
  const float* W1 = (const float*)d_in[2];  const float* b1 = (const float*)d_in[3];
  const float* W2 = (const float*)d_in[4];  const float* b2 = (const float*)d_in[5];
  const float* W3 = (const float*)d_in[6];  const float* b3 = (const float*)d_in[7];
  const float* cW1 = (const float*)d_in[8]; const float* cb1 = (const float*)d_in[9];
  const float* cW2 = (const float*)d_in[10]; const float* cb2 = (const float*)d_in[11];
  const int* eidx  = (const int*)d_in[12];
  const int* eattr = (const int*)d_in[13];

  const int N = in_sizes[0] / 128;
  const int E = in_sizes[13];
  const int* row = eidx;        // edge_index[0] = source
  const int* col = eidx + E;    // edge_index[1] = target

  float* out = (float*)d_out;

  // workspace layout, 16B-aligned slots (element counts rounded to x4)
  size_t off = 0;
  auto alloc4 = [&](size_t n) { size_t o = off; off += (n + 3) & ~(size_t)3; return o; };
  float* wsf = (float*)d_ws;
  int*   wsi = (int*)d_ws;

  float* dinv   = wsf + alloc4(N);
  float* snorm  = wsf + alloc4(N);
  int*   cnt    = wsi + alloc4(N);       // packed 3x10-bit per-attr counts
  int*   start  = wsi + alloc4(N + 1);
  int*   bsum   = wsi + alloc4(256);
  int*   rank   = wsi + alloc4(E);
  int*   srcs   = wsi + alloc4(E);
  float* wts    = wsf + alloc4(E);       // final normalized weights
  float* bufA   = wsf + alloc4((size_t)N * 128);
  float* bufB   = wsf + alloc4((size_t)N * 128);

  const int gN  = (N + 255) / 256;
  const int gE  = (E + 255) / 256;
  const int gA  = (N * 32 + 255) / 256;
  const int nb  = gN;  // scan blocks
  const int gGemm = 512;   // persistent: 2 blocks/CU

  // cnt must be zero before the interleaved hist in the layer-1 GEMM
  (void)hipMemsetAsync(cnt, 0, (size_t)N * sizeof(int), stream);

  // ---- layer-1 GEMM with interleaved packed edge histogram ----
  k_gemm<128, 0, false, true><<<gGemm, 256, 0, stream>>>(
      x, W1, nullptr, bufA, N, col, eattr, cnt, rank, E);

  // ---- CSR build: scan (+deg/dinv/snorm inline) -> fill (normalized) ----
  k_scan1<<<nb, 256, 0, stream>>>(cnt, start, bsum, edge_emb, dinv, snorm, N);
  k_scan2<<<1, 256, 0, stream>>>(bsum, nb);
  k_scan3<<<nb, 256, 0, stream>>>(start, bsum, N);
  k_fill<<<gE, 256, 0, stream>>>(eattr, edge_emb, row, col, rank, start,
                                 dinv, srcs, wts, E);

  // ---- layer 1 agg ----
  k_agg_csr<<<gA, 256, 0, stream>>>(bufA, start, srcs, wts, snorm, b1, bufB, N);
  // ---- layer 2 ----
  k_gemm<128, 0, true, false><<<gGemm, 256, 0, stream>>>(
      bufB, W2, nullptr, bufA, N, nullptr, nullptr, nullptr, nullptr, 0);
  k_agg_csr<<<gA, 256, 0, stream>>>(bufA, start, srcs, wts, snorm, b2, bufB, N);
  // ---- layer 3 ----
  k_gemm<128, 0, true, false><<<gGemm, 256, 0, stream>>>(
      bufB, W3, nullptr, bufA, N, nullptr, nullptr, nullptr, nullptr, 0);
  k_agg_csr<<<gA, 256, 0, stream>>>(bufA, start, srcs, wts, snorm, b3, bufB, N);

  // ---- classifier (two plain GEMMs, 2 blocks/CU each) ----
  k_gemm<128, 1, true, false><<<gGemm, 256, 0, stream>>>(
      bufB, cW1, cb1, bufA, N, nullptr, nullptr, nullptr, nullptr, 0);
  k_gemm<64, 2, false, false><<<gGemm, 256, 0, stream>>>(
      bufA, cW2, cb2, out, N, nullptr, nullptr, nullptr, nullptr, 0);
}